// Round 24
// baseline (118.667 us; speedup 1.0000x reference)
//
#include <hip/hip_runtime.h>
#include <hip/hip_bf16.h>

typedef __attribute__((ext_vector_type(4))) float f32x4;
typedef __attribute__((ext_vector_type(16))) float f32x16;
typedef __attribute__((ext_vector_type(8))) short bf16x8;
typedef __attribute__((ext_vector_type(4))) unsigned int uint4v;
typedef __attribute__((ext_vector_type(2))) unsigned int uint2v;

#define MFMA16(a, b, c) __builtin_amdgcn_mfma_f32_16x16x32_bf16(a, b, c, 0, 0, 0)
#define MFMA32(a, b, c) __builtin_amdgcn_mfma_f32_32x32x16_bf16(a, b, c, 0, 0, 0)

__device__ __forceinline__ unsigned short f2bf(float f) {
  union { float f; unsigned u; } v; v.f = f;
  unsigned r = v.u + 0x7fffu + ((v.u >> 16) & 1u);
  return (unsigned short)(r >> 16);
}
__device__ __forceinline__ unsigned pack2(float a, float b) {
  union { __hip_bfloat162 h2; unsigned u; } cv;
  cv.h2 = __hip_bfloat162(__float2bfloat16(a), __float2bfloat16(b));
  return cv.u;
}

// cross-half exchange (validated R10-R23)
__device__ __forceinline__ void swap32(unsigned a, unsigned b, int hi,
                                       unsigned& ox, unsigned& oy) {
#if __has_builtin(__builtin_amdgcn_permlane32_swap)
  uint2v r = __builtin_amdgcn_permlane32_swap(a, b, false, false);
  ox = r[0]; oy = r[1];
#else
  unsigned sb = __shfl_xor(b, 32);
  unsigned sa = __shfl_xor(a, 32);
  ox = hi ? sb : a;
  oy = hi ? b : sa;
#endif
}

// Fused Q + K + V projections in ONE dispatch (2048 blocks).
// Q/KV INTERLEAVED by block parity (even=Q, odd=KV) so the 2-phase KV blocks
// spread evenly across the dispatch tail instead of clustering at the end.
__global__ __launch_bounds__(256)
void proj_qkv_kernel(const float* __restrict__ image,
                     const float* __restrict__ Wq, const float* __restrict__ bq,
                     float qscale,
                     const float* __restrict__ smiles,
                     const float* __restrict__ Wk, const float* __restrict__ bk,
                     const float* __restrict__ Wv, const float* __restrict__ bv,
                     unsigned short* __restrict__ Qout,
                     unsigned short* __restrict__ Kout,
                     unsigned short* __restrict__ Vout)
{
  __shared__ __align__(16) unsigned short Ws[128][136];
  __shared__ __align__(16) unsigned short Xs[64][136];
  const int t = threadIdx.x;
  const int wid = t >> 6;
  const int lane = t & 63;
  const int ln = lane & 15, g = lane >> 4;
  const bool isQ = (blockIdx.x & 1) == 0;
  const long row0 = (long)(blockIdx.x >> 1) * 64;
  const float* x = isQ ? image : smiles;

#pragma unroll
  for (int i = 0; i < 8; ++i) {
    int idx = (i * 256 + t) * 4;
    int r = idx >> 7, c = idx & 127;
    const float4 x4 = *reinterpret_cast<const float4*>(x + row0 * 128 + idx);
    ushort4 xb;
    xb.x = f2bf(x4.x); xb.y = f2bf(x4.y); xb.z = f2bf(x4.z); xb.w = f2bf(x4.w);
    *reinterpret_cast<ushort4*>(&Xs[r][c]) = xb;
  }

  const float* W1 = isQ ? Wq : Wk;
  const float* b1 = isQ ? bq : bk;
  float bz[8];
#pragma unroll
  for (int tt = 0; tt < 8; ++tt) bz[tt] = b1[tt * 16 + ln];

#pragma unroll
  for (int i = 0; i < 16; ++i) {
    int idx = (i * 256 + t) * 4;
    int r = idx >> 7, c = idx & 127;
    const float4 w4 = *reinterpret_cast<const float4*>(W1 + idx);
    ushort4 wb;
    wb.x = f2bf(w4.x); wb.y = f2bf(w4.y); wb.z = f2bf(w4.z); wb.w = f2bf(w4.w);
    *reinterpret_cast<ushort4*>(&Ws[r][c]) = wb;
  }
  __syncthreads();

  f32x4 acc[8];
#pragma unroll
  for (int tt = 0; tt < 8; ++tt) acc[tt] = (f32x4){0.f, 0.f, 0.f, 0.f};
#pragma unroll
  for (int c = 0; c < 4; ++c) {
    bf16x8 af = *reinterpret_cast<const bf16x8*>(&Xs[wid * 16 + ln][c * 32 + g * 8]);
#pragma unroll
    for (int tt = 0; tt < 8; ++tt) {
      bf16x8 bfr = *reinterpret_cast<const bf16x8*>(&Ws[tt * 16 + ln][c * 32 + g * 8]);
      acc[tt] = MFMA16(af, bfr, acc[tt]);
    }
  }

  if (isQ) {
#pragma unroll
    for (int tt = 0; tt < 8; ++tt)
#pragma unroll
      for (int r = 0; r < 4; ++r) {
        long row = row0 + wid * 16 + g * 4 + r;
        Qout[row * 128 + tt * 16 + ln] = f2bf((acc[tt][r] + bz[tt]) * qscale);
      }
    return;
  }

#pragma unroll
  for (int tt = 0; tt < 8; ++tt)
#pragma unroll
    for (int r = 0; r < 4; ++r) {
      long row = row0 + wid * 16 + g * 4 + r;
      Kout[row * 128 + tt * 16 + ln] = f2bf(acc[tt][r] + bz[tt]);
    }

  __syncthreads();
#pragma unroll
  for (int i = 0; i < 16; ++i) {
    int idx = (i * 256 + t) * 4;
    int r = idx >> 7, c = idx & 127;
    const float4 w4 = *reinterpret_cast<const float4*>(Wv + idx);
    ushort4 wb;
    wb.x = f2bf(w4.x); wb.y = f2bf(w4.y); wb.z = f2bf(w4.z); wb.w = f2bf(w4.w);
    *reinterpret_cast<ushort4*>(&Ws[r][c]) = wb;
  }
  __syncthreads();

  float bzv[8];
#pragma unroll
  for (int tt = 0; tt < 8; ++tt) bzv[tt] = bv[tt * 16 + ln];
#pragma unroll
  for (int tt = 0; tt < 8; ++tt) acc[tt] = (f32x4){0.f, 0.f, 0.f, 0.f};
#pragma unroll
  for (int c = 0; c < 4; ++c) {
    bf16x8 af = *reinterpret_cast<const bf16x8*>(&Xs[wid * 16 + ln][c * 32 + g * 8]);
#pragma unroll
    for (int tt = 0; tt < 8; ++tt) {
      bf16x8 bfr = *reinterpret_cast<const bf16x8*>(&Ws[tt * 16 + ln][c * 32 + g * 8]);
      acc[tt] = MFMA16(af, bfr, acc[tt]);
    }
  }
#pragma unroll
  for (int tt = 0; tt < 8; ++tt)
#pragma unroll
    for (int r = 0; r < 4; ++r) {
      long row = row0 + wid * 16 + g * 4 + r;
      long bb = row >> 11, rr = row & 2047;
      Vout[(bb * 128 + tt * 16 + ln) * 2048 + rr] = f2bf(acc[tt][r] + bzv[tt]);
    }
}

// Flash attention — R23-proven body, UNCHANGED (92.2 us, absmax 5.86e-3).
// 8 waves x 32 q, KVBLK=64, single-barrier dbuf, T14 prefetch, defer-max,
// permlane P-exchange, fused Wd epilogue.
__global__ __launch_bounds__(512)
void attn_kernel(const unsigned short* __restrict__ Qg,
                 const unsigned short* __restrict__ Kg,
                 const unsigned short* __restrict__ Vtg,
                 const float* __restrict__ Wd,
                 const float* __restrict__ bd,
                 float* __restrict__ Out)
{
  __shared__ __align__(16) unsigned char smem[104448];
  auto Ks = reinterpret_cast<unsigned short (*)[64][136]>(smem);
  auto Vs = reinterpret_cast<unsigned short (*)[128][72]>(smem + 34816);

  const int t = threadIdx.x;          // 0..511
  const int lane = t & 63;
  const int q = lane & 31;
  const int hi = lane >> 5;
  const int wid = t >> 6;             // 0..7

  const int gbid = blockIdx.x;
  const int k_ = gbid >> 3, r_ = gbid & 7;
  const int b = r_ + 8 * (k_ >> 3);
  const int j = k_ & 7;
  const int q0 = j * 256 + wid * 32;

  const unsigned short* Qb = Qg + (long)b * 2048 * 128;
  const unsigned short* Kb = Kg + (long)b * 2048 * 128;
  const unsigned short* Vb = Vtg + (long)b * 128 * 2048;

  const int kr = t >> 3, kc = (t & 7) * 16;   // K tile [64][128]
  const int vc = t >> 2, vo = (t & 3) * 16;   // V^T tile [128][64]

  bf16x8 qf[8];
#pragma unroll
  for (int c = 0; c < 8; ++c)
    qf[c] = *reinterpret_cast<const bf16x8*>(
        Qb + (long)(q0 + q) * 128 + c * 16 + hi * 8);

  f32x16 o[4];
#pragma unroll
  for (int dc = 0; dc < 4; ++dc)
#pragma unroll
    for (int r = 0; r < 16; ++r) o[dc][r] = 0.f;
  float mrun = -1e30f;
  float lrun = 0.f;

  uint4v kregA = *reinterpret_cast<const uint4v*>(Kb + (long)kr * 128 + kc);
  uint4v kregB = *reinterpret_cast<const uint4v*>(Kb + (long)kr * 128 + kc + 8);
  uint4v vregA = *reinterpret_cast<const uint4v*>(Vb + (long)vc * 2048 + vo);
  uint4v vregB = *reinterpret_cast<const uint4v*>(Vb + (long)vc * 2048 + vo + 8);
  *reinterpret_cast<uint4v*>(&Ks[0][kr][kc]) = kregA;
  *reinterpret_cast<uint4v*>(&Ks[0][kr][kc + 8]) = kregB;
  *reinterpret_cast<uint4v*>(&Vs[0][vc][vo]) = vregA;
  *reinterpret_cast<uint4v*>(&Vs[0][vc][vo + 8]) = vregB;
  kregA = *reinterpret_cast<const uint4v*>(Kb + (long)(64 + kr) * 128 + kc);
  kregB = *reinterpret_cast<const uint4v*>(Kb + (long)(64 + kr) * 128 + kc + 8);
  vregA = *reinterpret_cast<const uint4v*>(Vb + (long)vc * 2048 + 64 + vo);
  vregB = *reinterpret_cast<const uint4v*>(Vb + (long)vc * 2048 + 64 + vo + 8);
  __syncthreads();

  for (int kt = 0; kt < 32; ++kt) {
    const int cur = kt & 1;

    if (kt < 31) {
      const int nb = cur ^ 1;
      *reinterpret_cast<uint4v*>(&Ks[nb][kr][kc]) = kregA;
      *reinterpret_cast<uint4v*>(&Ks[nb][kr][kc + 8]) = kregB;
      *reinterpret_cast<uint4v*>(&Vs[nb][vc][vo]) = vregA;
      *reinterpret_cast<uint4v*>(&Vs[nb][vc][vo + 8]) = vregB;
      if (kt < 30) {
        const int nv0 = (kt + 2) * 64;
        kregA = *reinterpret_cast<const uint4v*>(Kb + (long)(nv0 + kr) * 128 + kc);
        kregB = *reinterpret_cast<const uint4v*>(Kb + (long)(nv0 + kr) * 128 + kc + 8);
        vregA = *reinterpret_cast<const uint4v*>(Vb + (long)vc * 2048 + nv0 + vo);
        vregB = *reinterpret_cast<const uint4v*>(Vb + (long)vc * 2048 + nv0 + vo + 8);
      }
    }

    f32x16 st0, st1;
#pragma unroll
    for (int r = 0; r < 16; ++r) { st0[r] = 0.f; st1[r] = 0.f; }
    __builtin_amdgcn_s_setprio(1);
#pragma unroll
    for (int c = 0; c < 8; ++c) {
      bf16x8 kf0 = *reinterpret_cast<const bf16x8*>(&Ks[cur][q][c * 16 + hi * 8]);
      bf16x8 kf1 = *reinterpret_cast<const bf16x8*>(&Ks[cur][32 + q][c * 16 + hi * 8]);
      st0 = MFMA32(kf0, qf[c], st0);
      st1 = MFMA32(kf1, qf[c], st1);
    }
    __builtin_amdgcn_s_setprio(0);

    float mx[16];
#pragma unroll
    for (int r = 0; r < 16; ++r) mx[r] = fmaxf(st0[r], st1[r]);
#pragma unroll
    for (int r = 0; r < 8; ++r) mx[r] = fmaxf(mx[r], mx[r + 8]);
#pragma unroll
    for (int r = 0; r < 4; ++r) mx[r] = fmaxf(mx[r], mx[r + 4]);
    float tm = fmaxf(fmaxf(mx[0], mx[1]), fmaxf(mx[2], mx[3]));
    tm = fmaxf(tm, __shfl_xor(tm, 32));

    float mcur = mrun;
    if (!__all(tm <= mcur + 8.0f)) {
      float mnew = fmaxf(mcur, tm);
      float al = __builtin_amdgcn_exp2f(mcur - mnew);
      mrun = mnew;
      mcur = mnew;
      lrun *= al;
#pragma unroll
      for (int r = 0; r < 16; ++r) {
        float ar = __shfl(al, (r & 3) + 8 * (r >> 2) + 4 * hi);
#pragma unroll
        for (int dc = 0; dc < 4; ++dc) o[dc][r] *= ar;
      }
    }

    unsigned pk[16];
    float s[16];
#pragma unroll
    for (int j2 = 0; j2 < 8; ++j2) {
      float pa_ = __builtin_amdgcn_exp2f(st0[2 * j2] - mcur);
      float pb_ = __builtin_amdgcn_exp2f(st0[2 * j2 + 1] - mcur);
      s[j2] = pa_ + pb_;
      pk[j2] = pack2(pa_, pb_);
    }
#pragma unroll
    for (int j2 = 0; j2 < 8; ++j2) {
      float pa_ = __builtin_amdgcn_exp2f(st1[2 * j2] - mcur);
      float pb_ = __builtin_amdgcn_exp2f(st1[2 * j2 + 1] - mcur);
      s[8 + j2] = pa_ + pb_;
      pk[8 + j2] = pack2(pa_, pb_);
    }
#pragma unroll
    for (int j2 = 0; j2 < 8; ++j2) s[j2] += s[j2 + 8];
#pragma unroll
    for (int j2 = 0; j2 < 4; ++j2) s[j2] += s[j2 + 4];
    lrun += (s[0] + s[1]) + (s[2] + s[3]);

    union { unsigned u[4]; bf16x8 v; } pa0, pa1, pa2, pa3;
    swap32(pk[0],  pk[2],  hi, pa0.u[0], pa0.u[2]);
    swap32(pk[1],  pk[3],  hi, pa0.u[1], pa0.u[3]);
    swap32(pk[4],  pk[6],  hi, pa1.u[0], pa1.u[2]);
    swap32(pk[5],  pk[7],  hi, pa1.u[1], pa1.u[3]);
    swap32(pk[8],  pk[10], hi, pa2.u[0], pa2.u[2]);
    swap32(pk[9],  pk[11], hi, pa2.u[1], pa2.u[3]);
    swap32(pk[12], pk[14], hi, pa3.u[0], pa3.u[2]);
    swap32(pk[13], pk[15], hi, pa3.u[1], pa3.u[3]);

    __builtin_amdgcn_s_setprio(1);
#pragma unroll
    for (int dc = 0; dc < 4; ++dc) {
      bf16x8 vf0 = *reinterpret_cast<const bf16x8*>(&Vs[cur][dc * 32 + q][hi * 8]);
      bf16x8 vf1 = *reinterpret_cast<const bf16x8*>(&Vs[cur][dc * 32 + q][16 + hi * 8]);
      bf16x8 vf2 = *reinterpret_cast<const bf16x8*>(&Vs[cur][dc * 32 + q][32 + hi * 8]);
      bf16x8 vf3 = *reinterpret_cast<const bf16x8*>(&Vs[cur][dc * 32 + q][48 + hi * 8]);
      o[dc] = MFMA32(pa0.v, vf0, o[dc]);
      o[dc] = MFMA32(pa1.v, vf1, o[dc]);
      o[dc] = MFMA32(pa2.v, vf2, o[dc]);
      o[dc] = MFMA32(pa3.v, vf3, o[dc]);
    }
    __builtin_amdgcn_s_setprio(0);

    __syncthreads();
  }

  // ---------- fused output projection: out = O @ Wd^T + bd ----------
  auto Wds = reinterpret_cast<unsigned short (*)[136]>(smem);
  auto Os  = reinterpret_cast<unsigned short (*)[136]>(smem + 34816 + wid * 8704);

#pragma unroll
  for (int i = 0; i < 8; ++i) {
    int idx = (i * 512 + t) * 4;
    int r = idx >> 7, c = idx & 127;
    const float4 w4 = *reinterpret_cast<const float4*>(Wd + idx);
    ushort4 wb;
    wb.x = f2bf(w4.x); wb.y = f2bf(w4.y); wb.z = f2bf(w4.z); wb.w = f2bf(w4.w);
    *reinterpret_cast<ushort4*>(&Wds[r][c]) = wb;
  }

  float ltot = lrun + __shfl_xor(lrun, 32);
  float inv = 1.f / ltot;
#pragma unroll
  for (int r = 0; r < 16; ++r) {
    const int qr = (r & 3) + 8 * (r >> 2) + 4 * hi;
    float invr = __shfl(inv, qr);
#pragma unroll
    for (int dc = 0; dc < 4; ++dc)
      Os[qr][dc * 32 + q] = f2bf(o[dc][r] * invr);
  }
  __syncthreads();

  f32x16 o2[4];
#pragma unroll
  for (int cc = 0; cc < 4; ++cc)
#pragma unroll
    for (int r = 0; r < 16; ++r) o2[cc][r] = 0.f;
  __builtin_amdgcn_s_setprio(1);
#pragma unroll
  for (int c = 0; c < 8; ++c) {
    bf16x8 af = *reinterpret_cast<const bf16x8*>(&Os[q][c * 16 + hi * 8]);
#pragma unroll
    for (int cc = 0; cc < 4; ++cc) {
      bf16x8 bfr = *reinterpret_cast<const bf16x8*>(&Wds[cc * 32 + q][c * 16 + hi * 8]);
      o2[cc] = MFMA32(af, bfr, o2[cc]);
    }
  }
  __builtin_amdgcn_s_setprio(0);

  float bdv[4];
#pragma unroll
  for (int cc = 0; cc < 4; ++cc) bdv[cc] = bd[cc * 32 + q];

#pragma unroll
  for (int r = 0; r < 16; ++r) {
    const int qr = (r & 3) + 8 * (r >> 2) + 4 * hi;
    long row = (long)b * 2048 + q0 + qr;
#pragma unroll
    for (int cc = 0; cc < 4; ++cc)
      Out[row * 128 + cc * 32 + q] = o2[cc][r] + bdv[cc];
  }
}

extern "C" void kernel_launch(void* const* d_in, const int* in_sizes, int n_in,
                              void* d_out, int out_size, void* d_ws, size_t ws_size,
                              hipStream_t stream)
{
  (void)in_sizes; (void)n_in; (void)out_size; (void)ws_size;
  const float* smiles = (const float*)d_in[0];
  const float* image  = (const float*)d_in[1];
  const float* Wv = (const float*)d_in[2]; const float* bv = (const float*)d_in[3];
  const float* Wk = (const float*)d_in[4]; const float* bk = (const float*)d_in[5];
  const float* Wq = (const float*)d_in[6]; const float* bq = (const float*)d_in[7];
  const float* Wd = (const float*)d_in[8]; const float* bd = (const float*)d_in[9];

  unsigned short* Qw = (unsigned short*)d_ws;          // [32][2048][128] bf16
  unsigned short* Kw = Qw + 8388608;                   // [32][2048][128] bf16
  unsigned short* Vw = Kw + 8388608;                   // [32][128][2048] bf16 (V^T)

  const float qscale = 1.4426950408889634f * 0.08838834764831845f;

  proj_qkv_kernel<<<dim3(2048), dim3(256), 0, stream>>>(image, Wq, bq, qscale,
                                                        smiles, Wk, bk, Wv, bv,
                                                        Qw, Kw, Vw);
  attn_kernel<<<dim3(256), dim3(512), 0, stream>>>(Qw, Kw, Vw, Wd, bd, (float*)d_out);
}

// Round 25
// 113.970 us; speedup vs baseline: 1.0412x; 1.0412x over previous
//
#include <hip/hip_runtime.h>
#include <hip/hip_bf16.h>

typedef __attribute__((ext_vector_type(4))) float f32x4;
typedef __attribute__((ext_vector_type(16))) float f32x16;
typedef __attribute__((ext_vector_type(8))) short bf16x8;
typedef __attribute__((ext_vector_type(4))) unsigned int uint4v;
typedef __attribute__((ext_vector_type(2))) unsigned int uint2v;

#define MFMA16(a, b, c) __builtin_amdgcn_mfma_f32_16x16x32_bf16(a, b, c, 0, 0, 0)
#define MFMA32(a, b, c) __builtin_amdgcn_mfma_f32_32x32x16_bf16(a, b, c, 0, 0, 0)

__device__ __forceinline__ unsigned short f2bf(float f) {
  union { float f; unsigned u; } v; v.f = f;
  unsigned r = v.u + 0x7fffu + ((v.u >> 16) & 1u);
  return (unsigned short)(r >> 16);
}
__device__ __forceinline__ unsigned pack2(float a, float b) {
  union { __hip_bfloat162 h2; unsigned u; } cv;
  cv.h2 = __hip_bfloat162(__float2bfloat16(a), __float2bfloat16(b));
  return cv.u;
}

// cross-half exchange (validated R10-R23)
__device__ __forceinline__ void swap32(unsigned a, unsigned b, int hi,
                                       unsigned& ox, unsigned& oy) {
#if __has_builtin(__builtin_amdgcn_permlane32_swap)
  uint2v r = __builtin_amdgcn_permlane32_swap(a, b, false, false);
  ox = r[0]; oy = r[1];
#else
  unsigned sb = __shfl_xor(b, 32);
  unsigned sa = __shfl_xor(a, 32);
  ox = hi ? sb : a;
  oy = hi ? b : sa;
#endif
}

// Fused Q + K + V projections in ONE dispatch (2048 blocks) — R18/R23-proven
// contiguous mapping (blocks 0..1023 = Q from image, 1024..2047 = K+V from
// smiles). R24 proved parity-interleaving these REGRESSES (input-stream
// locality loss > tail-balance gain).
__global__ __launch_bounds__(256)
void proj_qkv_kernel(const float* __restrict__ image,
                     const float* __restrict__ Wq, const float* __restrict__ bq,
                     float qscale,
                     const float* __restrict__ smiles,
                     const float* __restrict__ Wk, const float* __restrict__ bk,
                     const float* __restrict__ Wv, const float* __restrict__ bv,
                     unsigned short* __restrict__ Qout,
                     unsigned short* __restrict__ Kout,
                     unsigned short* __restrict__ Vout)
{
  __shared__ __align__(16) unsigned short Ws[128][136];
  __shared__ __align__(16) unsigned short Xs[64][136];
  const int t = threadIdx.x;
  const int wid = t >> 6;
  const int lane = t & 63;
  const int ln = lane & 15, g = lane >> 4;
  const bool isQ = blockIdx.x < 1024;
  const long row0 = (long)(isQ ? blockIdx.x : blockIdx.x - 1024) * 64;
  const float* x = isQ ? image : smiles;

#pragma unroll
  for (int i = 0; i < 8; ++i) {
    int idx = (i * 256 + t) * 4;
    int r = idx >> 7, c = idx & 127;
    const float4 x4 = *reinterpret_cast<const float4*>(x + row0 * 128 + idx);
    ushort4 xb;
    xb.x = f2bf(x4.x); xb.y = f2bf(x4.y); xb.z = f2bf(x4.z); xb.w = f2bf(x4.w);
    *reinterpret_cast<ushort4*>(&Xs[r][c]) = xb;
  }

  const float* W1 = isQ ? Wq : Wk;
  const float* b1 = isQ ? bq : bk;
  float bz[8];
#pragma unroll
  for (int tt = 0; tt < 8; ++tt) bz[tt] = b1[tt * 16 + ln];

#pragma unroll
  for (int i = 0; i < 16; ++i) {
    int idx = (i * 256 + t) * 4;
    int r = idx >> 7, c = idx & 127;
    const float4 w4 = *reinterpret_cast<const float4*>(W1 + idx);
    ushort4 wb;
    wb.x = f2bf(w4.x); wb.y = f2bf(w4.y); wb.z = f2bf(w4.z); wb.w = f2bf(w4.w);
    *reinterpret_cast<ushort4*>(&Ws[r][c]) = wb;
  }
  __syncthreads();

  f32x4 acc[8];
#pragma unroll
  for (int tt = 0; tt < 8; ++tt) acc[tt] = (f32x4){0.f, 0.f, 0.f, 0.f};
#pragma unroll
  for (int c = 0; c < 4; ++c) {
    bf16x8 af = *reinterpret_cast<const bf16x8*>(&Xs[wid * 16 + ln][c * 32 + g * 8]);
#pragma unroll
    for (int tt = 0; tt < 8; ++tt) {
      bf16x8 bfr = *reinterpret_cast<const bf16x8*>(&Ws[tt * 16 + ln][c * 32 + g * 8]);
      acc[tt] = MFMA16(af, bfr, acc[tt]);
    }
  }

  if (isQ) {
#pragma unroll
    for (int tt = 0; tt < 8; ++tt)
#pragma unroll
      for (int r = 0; r < 4; ++r) {
        long row = row0 + wid * 16 + g * 4 + r;
        Qout[row * 128 + tt * 16 + ln] = f2bf((acc[tt][r] + bz[tt]) * qscale);
      }
    return;
  }

#pragma unroll
  for (int tt = 0; tt < 8; ++tt)
#pragma unroll
    for (int r = 0; r < 4; ++r) {
      long row = row0 + wid * 16 + g * 4 + r;
      Kout[row * 128 + tt * 16 + ln] = f2bf(acc[tt][r] + bz[tt]);
    }

  __syncthreads();
#pragma unroll
  for (int i = 0; i < 16; ++i) {
    int idx = (i * 256 + t) * 4;
    int r = idx >> 7, c = idx & 127;
    const float4 w4 = *reinterpret_cast<const float4*>(Wv + idx);
    ushort4 wb;
    wb.x = f2bf(w4.x); wb.y = f2bf(w4.y); wb.z = f2bf(w4.z); wb.w = f2bf(w4.w);
    *reinterpret_cast<ushort4*>(&Ws[r][c]) = wb;
  }
  __syncthreads();

  float bzv[8];
#pragma unroll
  for (int tt = 0; tt < 8; ++tt) bzv[tt] = bv[tt * 16 + ln];
#pragma unroll
  for (int tt = 0; tt < 8; ++tt) acc[tt] = (f32x4){0.f, 0.f, 0.f, 0.f};
#pragma unroll
  for (int c = 0; c < 4; ++c) {
    bf16x8 af = *reinterpret_cast<const bf16x8*>(&Xs[wid * 16 + ln][c * 32 + g * 8]);
#pragma unroll
    for (int tt = 0; tt < 8; ++tt) {
      bf16x8 bfr = *reinterpret_cast<const bf16x8*>(&Ws[tt * 16 + ln][c * 32 + g * 8]);
      acc[tt] = MFMA16(af, bfr, acc[tt]);
    }
  }
#pragma unroll
  for (int tt = 0; tt < 8; ++tt)
#pragma unroll
    for (int r = 0; r < 4; ++r) {
      long row = row0 + wid * 16 + g * 4 + r;
      long bb = row >> 11, rr = row & 2047;
      Vout[(bb * 128 + tt * 16 + ln) * 2048 + rr] = f2bf(acc[tt][r] + bzv[tt]);
    }
}

// Flash attention — R23-proven body, UNCHANGED (92.2 us, absmax 5.86e-3).
// 8 waves x 32 q, KVBLK=64, single-barrier dbuf, T14 prefetch, defer-max,
// permlane P-exchange, fused Wd epilogue.
__global__ __launch_bounds__(512)
void attn_kernel(const unsigned short* __restrict__ Qg,
                 const unsigned short* __restrict__ Kg,
                 const unsigned short* __restrict__ Vtg,
                 const float* __restrict__ Wd,
                 const float* __restrict__ bd,
                 float* __restrict__ Out)
{
  __shared__ __align__(16) unsigned char smem[104448];
  auto Ks = reinterpret_cast<unsigned short (*)[64][136]>(smem);
  auto Vs = reinterpret_cast<unsigned short (*)[128][72]>(smem + 34816);

  const int t = threadIdx.x;          // 0..511
  const int lane = t & 63;
  const int q = lane & 31;
  const int hi = lane >> 5;
  const int wid = t >> 6;             // 0..7

  const int gbid = blockIdx.x;
  const int k_ = gbid >> 3, r_ = gbid & 7;
  const int b = r_ + 8 * (k_ >> 3);
  const int j = k_ & 7;
  const int q0 = j * 256 + wid * 32;

  const unsigned short* Qb = Qg + (long)b * 2048 * 128;
  const unsigned short* Kb = Kg + (long)b * 2048 * 128;
  const unsigned short* Vb = Vtg + (long)b * 128 * 2048;

  const int kr = t >> 3, kc = (t & 7) * 16;   // K tile [64][128]
  const int vc = t >> 2, vo = (t & 3) * 16;   // V^T tile [128][64]

  bf16x8 qf[8];
#pragma unroll
  for (int c = 0; c < 8; ++c)
    qf[c] = *reinterpret_cast<const bf16x8*>(
        Qb + (long)(q0 + q) * 128 + c * 16 + hi * 8);

  f32x16 o[4];
#pragma unroll
  for (int dc = 0; dc < 4; ++dc)
#pragma unroll
    for (int r = 0; r < 16; ++r) o[dc][r] = 0.f;
  float mrun = -1e30f;
  float lrun = 0.f;

  uint4v kregA = *reinterpret_cast<const uint4v*>(Kb + (long)kr * 128 + kc);
  uint4v kregB = *reinterpret_cast<const uint4v*>(Kb + (long)kr * 128 + kc + 8);
  uint4v vregA = *reinterpret_cast<const uint4v*>(Vb + (long)vc * 2048 + vo);
  uint4v vregB = *reinterpret_cast<const uint4v*>(Vb + (long)vc * 2048 + vo + 8);
  *reinterpret_cast<uint4v*>(&Ks[0][kr][kc]) = kregA;
  *reinterpret_cast<uint4v*>(&Ks[0][kr][kc + 8]) = kregB;
  *reinterpret_cast<uint4v*>(&Vs[0][vc][vo]) = vregA;
  *reinterpret_cast<uint4v*>(&Vs[0][vc][vo + 8]) = vregB;
  kregA = *reinterpret_cast<const uint4v*>(Kb + (long)(64 + kr) * 128 + kc);
  kregB = *reinterpret_cast<const uint4v*>(Kb + (long)(64 + kr) * 128 + kc + 8);
  vregA = *reinterpret_cast<const uint4v*>(Vb + (long)vc * 2048 + 64 + vo);
  vregB = *reinterpret_cast<const uint4v*>(Vb + (long)vc * 2048 + 64 + vo + 8);
  __syncthreads();

  for (int kt = 0; kt < 32; ++kt) {
    const int cur = kt & 1;

    if (kt < 31) {
      const int nb = cur ^ 1;
      *reinterpret_cast<uint4v*>(&Ks[nb][kr][kc]) = kregA;
      *reinterpret_cast<uint4v*>(&Ks[nb][kr][kc + 8]) = kregB;
      *reinterpret_cast<uint4v*>(&Vs[nb][vc][vo]) = vregA;
      *reinterpret_cast<uint4v*>(&Vs[nb][vc][vo + 8]) = vregB;
      if (kt < 30) {
        const int nv0 = (kt + 2) * 64;
        kregA = *reinterpret_cast<const uint4v*>(Kb + (long)(nv0 + kr) * 128 + kc);
        kregB = *reinterpret_cast<const uint4v*>(Kb + (long)(nv0 + kr) * 128 + kc + 8);
        vregA = *reinterpret_cast<const uint4v*>(Vb + (long)vc * 2048 + nv0 + vo);
        vregB = *reinterpret_cast<const uint4v*>(Vb + (long)vc * 2048 + nv0 + vo + 8);
      }
    }

    f32x16 st0, st1;
#pragma unroll
    for (int r = 0; r < 16; ++r) { st0[r] = 0.f; st1[r] = 0.f; }
    __builtin_amdgcn_s_setprio(1);
#pragma unroll
    for (int c = 0; c < 8; ++c) {
      bf16x8 kf0 = *reinterpret_cast<const bf16x8*>(&Ks[cur][q][c * 16 + hi * 8]);
      bf16x8 kf1 = *reinterpret_cast<const bf16x8*>(&Ks[cur][32 + q][c * 16 + hi * 8]);
      st0 = MFMA32(kf0, qf[c], st0);
      st1 = MFMA32(kf1, qf[c], st1);
    }
    __builtin_amdgcn_s_setprio(0);

    float mx[16];
#pragma unroll
    for (int r = 0; r < 16; ++r) mx[r] = fmaxf(st0[r], st1[r]);
#pragma unroll
    for (int r = 0; r < 8; ++r) mx[r] = fmaxf(mx[r], mx[r + 8]);
#pragma unroll
    for (int r = 0; r < 4; ++r) mx[r] = fmaxf(mx[r], mx[r + 4]);
    float tm = fmaxf(fmaxf(mx[0], mx[1]), fmaxf(mx[2], mx[3]));
    tm = fmaxf(tm, __shfl_xor(tm, 32));

    float mcur = mrun;
    if (!__all(tm <= mcur + 8.0f)) {
      float mnew = fmaxf(mcur, tm);
      float al = __builtin_amdgcn_exp2f(mcur - mnew);
      mrun = mnew;
      mcur = mnew;
      lrun *= al;
#pragma unroll
      for (int r = 0; r < 16; ++r) {
        float ar = __shfl(al, (r & 3) + 8 * (r >> 2) + 4 * hi);
#pragma unroll
        for (int dc = 0; dc < 4; ++dc) o[dc][r] *= ar;
      }
    }

    unsigned pk[16];
    float s[16];
#pragma unroll
    for (int j2 = 0; j2 < 8; ++j2) {
      float pa_ = __builtin_amdgcn_exp2f(st0[2 * j2] - mcur);
      float pb_ = __builtin_amdgcn_exp2f(st0[2 * j2 + 1] - mcur);
      s[j2] = pa_ + pb_;
      pk[j2] = pack2(pa_, pb_);
    }
#pragma unroll
    for (int j2 = 0; j2 < 8; ++j2) {
      float pa_ = __builtin_amdgcn_exp2f(st1[2 * j2] - mcur);
      float pb_ = __builtin_amdgcn_exp2f(st1[2 * j2 + 1] - mcur);
      s[8 + j2] = pa_ + pb_;
      pk[8 + j2] = pack2(pa_, pb_);
    }
#pragma unroll
    for (int j2 = 0; j2 < 8; ++j2) s[j2] += s[j2 + 8];
#pragma unroll
    for (int j2 = 0; j2 < 4; ++j2) s[j2] += s[j2 + 4];
    lrun += (s[0] + s[1]) + (s[2] + s[3]);

    union { unsigned u[4]; bf16x8 v; } pa0, pa1, pa2, pa3;
    swap32(pk[0],  pk[2],  hi, pa0.u[0], pa0.u[2]);
    swap32(pk[1],  pk[3],  hi, pa0.u[1], pa0.u[3]);
    swap32(pk[4],  pk[6],  hi, pa1.u[0], pa1.u[2]);
    swap32(pk[5],  pk[7],  hi, pa1.u[1], pa1.u[3]);
    swap32(pk[8],  pk[10], hi, pa2.u[0], pa2.u[2]);
    swap32(pk[9],  pk[11], hi, pa2.u[1], pa2.u[3]);
    swap32(pk[12], pk[14], hi, pa3.u[0], pa3.u[2]);
    swap32(pk[13], pk[15], hi, pa3.u[1], pa3.u[3]);

    __builtin_amdgcn_s_setprio(1);
#pragma unroll
    for (int dc = 0; dc < 4; ++dc) {
      bf16x8 vf0 = *reinterpret_cast<const bf16x8*>(&Vs[cur][dc * 32 + q][hi * 8]);
      bf16x8 vf1 = *reinterpret_cast<const bf16x8*>(&Vs[cur][dc * 32 + q][16 + hi * 8]);
      bf16x8 vf2 = *reinterpret_cast<const bf16x8*>(&Vs[cur][dc * 32 + q][32 + hi * 8]);
      bf16x8 vf3 = *reinterpret_cast<const bf16x8*>(&Vs[cur][dc * 32 + q][48 + hi * 8]);
      o[dc] = MFMA32(pa0.v, vf0, o[dc]);
      o[dc] = MFMA32(pa1.v, vf1, o[dc]);
      o[dc] = MFMA32(pa2.v, vf2, o[dc]);
      o[dc] = MFMA32(pa3.v, vf3, o[dc]);
    }
    __builtin_amdgcn_s_setprio(0);

    __syncthreads();
  }

  // ---------- fused output projection: out = O @ Wd^T + bd ----------
  auto Wds = reinterpret_cast<unsigned short (*)[136]>(smem);
  auto Os  = reinterpret_cast<unsigned short (*)[136]>(smem + 34816 + wid * 8704);

#pragma unroll
  for (int i = 0; i < 8; ++i) {
    int idx = (i * 512 + t) * 4;
    int r = idx >> 7, c = idx & 127;
    const float4 w4 = *reinterpret_cast<const float4*>(Wd + idx);
    ushort4 wb;
    wb.x = f2bf(w4.x); wb.y = f2bf(w4.y); wb.z = f2bf(w4.z); wb.w = f2bf(w4.w);
    *reinterpret_cast<ushort4*>(&Wds[r][c]) = wb;
  }

  float ltot = lrun + __shfl_xor(lrun, 32);
  float inv = 1.f / ltot;
#pragma unroll
  for (int r = 0; r < 16; ++r) {
    const int qr = (r & 3) + 8 * (r >> 2) + 4 * hi;
    float invr = __shfl(inv, qr);
#pragma unroll
    for (int dc = 0; dc < 4; ++dc)
      Os[qr][dc * 32 + q] = f2bf(o[dc][r] * invr);
  }
  __syncthreads();

  f32x16 o2[4];
#pragma unroll
  for (int cc = 0; cc < 4; ++cc)
#pragma unroll
    for (int r = 0; r < 16; ++r) o2[cc][r] = 0.f;
  __builtin_amdgcn_s_setprio(1);
#pragma unroll
  for (int c = 0; c < 8; ++c) {
    bf16x8 af = *reinterpret_cast<const bf16x8*>(&Os[q][c * 16 + hi * 8]);
#pragma unroll
    for (int cc = 0; cc < 4; ++cc) {
      bf16x8 bfr = *reinterpret_cast<const bf16x8*>(&Wds[cc * 32 + q][c * 16 + hi * 8]);
      o2[cc] = MFMA32(af, bfr, o2[cc]);
    }
  }
  __builtin_amdgcn_s_setprio(0);

  float bdv[4];
#pragma unroll
  for (int cc = 0; cc < 4; ++cc) bdv[cc] = bd[cc * 32 + q];

#pragma unroll
  for (int r = 0; r < 16; ++r) {
    const int qr = (r & 3) + 8 * (r >> 2) + 4 * hi;
    long row = (long)b * 2048 + q0 + qr;
#pragma unroll
    for (int cc = 0; cc < 4; ++cc)
      Out[row * 128 + cc * 32 + q] = o2[cc][r] + bdv[cc];
  }
}

extern "C" void kernel_launch(void* const* d_in, const int* in_sizes, int n_in,
                              void* d_out, int out_size, void* d_ws, size_t ws_size,
                              hipStream_t stream)
{
  (void)in_sizes; (void)n_in; (void)out_size; (void)ws_size;
  const float* smiles = (const float*)d_in[0];
  const float* image  = (const float*)d_in[1];
  const float* Wv = (const float*)d_in[2]; const float* bv = (const float*)d_in[3];
  const float* Wk = (const float*)d_in[4]; const float* bk = (const float*)d_in[5];
  const float* Wq = (const float*)d_in[6]; const float* bq = (const float*)d_in[7];
  const float* Wd = (const float*)d_in[8]; const float* bd = (const float*)d_in[9];

  unsigned short* Qw = (unsigned short*)d_ws;          // [32][2048][128] bf16
  unsigned short* Kw = Qw + 8388608;                   // [32][2048][128] bf16
  unsigned short* Vw = Kw + 8388608;                   // [32][128][2048] bf16 (V^T)

  const float qscale = 1.4426950408889634f * 0.08838834764831845f;

  proj_qkv_kernel<<<dim3(2048), dim3(256), 0, stream>>>(image, Wq, bq, qscale,
                                                        smiles, Wk, bk, Wv, bv,
                                                        Qw, Kw, Vw);
  attn_kernel<<<dim3(256), dim3(512), 0, stream>>>(Qw, Kw, Vw, Wd, bd, (float*)d_out);
}